// Round 1
// baseline (341.109 us; speedup 1.0000x reference)
//
#include <hip/hip_runtime.h>
#include <stdint.h>

// HMPNN layer: two NNConv(sum-agg) + sigmoid, concat, Linear(32,32), sigmoid.
// Key reassociation: agg[d,o] = sum_e sum_f attr[e,f] * y[src_e,f,o],
// y[n,f,o] = sum_i x_src[n,i]*w_msg[f,i,o]  (node-level, 16x less work than per-edge).

#define NN 50000
#define EE 800000
#define YROW 272   // 17*16: 16 attr rows + 1 bias row

__device__ __forceinline__ float bf2f(unsigned short u) {
    union { unsigned int i; float f; } v; v.i = ((unsigned int)u) << 16; return v.f;
}
__device__ __forceinline__ unsigned short f2bf(float f) {
    union { float fl; unsigned int i; } v; v.fl = f;
    unsigned int x = v.i;
    x += 0x7FFFu + ((x >> 16) & 1u);   // round-to-nearest-even
    return (unsigned short)(x >> 16);
}

// y[n, f*16+o] = sum_i x[n,i] * w_msg[f,i,o]  (f<16);  f==16 row: sum_i x[n,i]*b_msg[i,o]
__global__ __launch_bounds__(256) void build_y(
    const float* __restrict__ x, const float* __restrict__ w_msg,
    const float* __restrict__ b_msg, unsigned short* __restrict__ y)
{
    __shared__ float sw[17 * 256];
    int tid = threadIdx.x;
    for (int idx = tid; idx < 17 * 256; idx += 256)
        sw[idx] = (idx < 4096) ? w_msg[idx] : b_msg[idx - 4096];
    __syncthreads();

    int n = blockIdx.x * 16 + (tid >> 4);
    if (n >= NN) return;
    int o = tid & 15;
    int lane = tid & 63;
    int gb = lane & ~15;

    float xv = x[n * 16 + o];          // coalesced: wave reads 64 consecutive floats
    float xi[16];
    #pragma unroll
    for (int i = 0; i < 16; ++i) xi[i] = __shfl(xv, gb + i);

    #pragma unroll
    for (int f = 0; f < 17; ++f) {
        float acc = 0.f;
        #pragma unroll
        for (int i = 0; i < 16; ++i)
            acc += xi[i] * sw[f * 256 + i * 16 + o];
        y[(size_t)n * YROW + f * 16 + o] = f2bf(acc);
    }
}

// One edge per 16-lane group; lane o owns output channel o.
__global__ __launch_bounds__(256) void edge_msg(
    const int* __restrict__ eidx, const float* __restrict__ attr,
    const unsigned short* __restrict__ y, float* __restrict__ agg)
{
    int tid = threadIdx.x;
    int e = blockIdx.x * 16 + (tid >> 4);
    if (e >= EE) return;
    int o = tid & 15;
    int lane = tid & 63;
    int gb = lane & ~15;

    int src = eidx[e];
    int dst = eidx[EE + e];
    float av = attr[e * 16 + o];       // lane o holds attr[e,o]
    const unsigned short* yr = y + (size_t)src * YROW;

    float acc = bf2f(yr[256 + o]);     // bias row
    #pragma unroll
    for (int f = 0; f < 16; ++f) {
        float af = __shfl(av, gb + f); // broadcast attr[e,f] across the group
        acc += af * bf2f(yr[f * 16 + o]);
    }
    atomicAdd(&agg[(size_t)dst * 16 + o], acc);
}

// out[n,d] = sigmoid( sum_j h[j]*w_lin[j,d] + b_lin[d] ),
// h[j<16] = sigmoid(agg_a[n,j] + x_indivi[n,:]@root_a[:,j] + bias_a[j]), j>=16 -> b.
__global__ __launch_bounds__(256) void finalize(
    const float* __restrict__ xind,
    const float* __restrict__ agg_a, const float* __restrict__ agg_b,
    const float* __restrict__ root_a, const float* __restrict__ bias_a,
    const float* __restrict__ root_b, const float* __restrict__ bias_b,
    const float* __restrict__ w_lin, const float* __restrict__ b_lin,
    float* __restrict__ out)
{
    int tid = threadIdx.x;
    int n = blockIdx.x * 8 + (tid >> 5);
    if (n >= NN) return;
    int d = tid & 31;
    int lane = tid & 63;
    int gb32 = lane & ~31;

    float xv = xind[n * 16 + (d & 15)];   // lanes gb32..gb32+15 hold x[n,0..15]

    int j = d & 15;
    const float* root = (d < 16) ? root_a : root_b;
    const float* bias = (d < 16) ? bias_a : bias_b;
    const float* agg  = (d < 16) ? agg_a  : agg_b;

    float acc = agg[n * 16 + j] + bias[j];
    #pragma unroll
    for (int i = 0; i < 16; ++i) {
        float xiv = __shfl(xv, gb32 + i);
        acc += xiv * root[i * 16 + j];
    }
    float h = 1.f / (1.f + __expf(-acc));

    float acc2 = b_lin[d];
    #pragma unroll
    for (int jj = 0; jj < 32; ++jj) {
        float hj = __shfl(h, gb32 + jj);
        acc2 += hj * w_lin[jj * 32 + d];
    }
    out[(size_t)n * 32 + d] = 1.f / (1.f + __expf(-acc2));
}

extern "C" void kernel_launch(void* const* d_in, const int* in_sizes, int n_in,
                              void* d_out, int out_size, void* d_ws, size_t ws_size,
                              hipStream_t stream) {
    (void)in_sizes; (void)n_in; (void)out_size; (void)ws_size;
    const float* x_indivi = (const float*)d_in[0];
    const float* x_src_a  = (const float*)d_in[1];
    const float* x_src_b  = (const float*)d_in[2];
    const int*   ei_a     = (const int*)d_in[3];
    const int*   ei_b     = (const int*)d_in[4];
    const float* ea_a     = (const float*)d_in[5];
    const float* ea_b     = (const float*)d_in[6];
    const float* w_msg_a  = (const float*)d_in[7];
    const float* b_msg_a  = (const float*)d_in[8];
    const float* root_a   = (const float*)d_in[9];
    const float* bias_a   = (const float*)d_in[10];
    const float* w_msg_b  = (const float*)d_in[11];
    const float* b_msg_b  = (const float*)d_in[12];
    const float* root_b   = (const float*)d_in[13];
    const float* bias_b   = (const float*)d_in[14];
    const float* w_lin    = (const float*)d_in[15];
    const float* b_lin    = (const float*)d_in[16];
    float* out = (float*)d_out;

    char* ws = (char*)d_ws;
    size_t off = 0;
    unsigned short* y_a = (unsigned short*)(ws + off); off += (size_t)NN * YROW * 2; // 27.2 MB
    unsigned short* y_b = (unsigned short*)(ws + off); off += (size_t)NN * YROW * 2; // 27.2 MB
    float* agg_a = (float*)(ws + off); off += (size_t)NN * 16 * 4;                   // 3.2 MB
    float* agg_b = (float*)(ws + off); off += (size_t)NN * 16 * 4;                   // 3.2 MB

    // agg buffers are accumulated into -> must start at zero (ws is 0xAA-poisoned).
    hipMemsetAsync(agg_a, 0, (size_t)NN * 16 * 4 * 2, stream);

    build_y<<<(NN + 15) / 16, 256, 0, stream>>>(x_src_a, w_msg_a, b_msg_a, y_a);
    build_y<<<(NN + 15) / 16, 256, 0, stream>>>(x_src_b, w_msg_b, b_msg_b, y_b);

    edge_msg<<<(EE + 15) / 16, 256, 0, stream>>>(ei_a, ea_a, y_a, agg_a);
    edge_msg<<<(EE + 15) / 16, 256, 0, stream>>>(ei_b, ea_b, y_b, agg_b);

    finalize<<<(NN + 7) / 8, 256, 0, stream>>>(
        x_indivi, agg_a, agg_b, root_a, bias_a, root_b, bias_b, w_lin, b_lin, out);
}